// Round 2
// baseline (8067.684 us; speedup 1.0000x reference)
//
#include <hip/hip_runtime.h>
#include <hip/hip_bf16.h>

#define TT 4096
#define BATCH 128
#define HID 64
#define CK 32              // chunk size
#define NCH (TT / CK)      // 128 chunks
#define NSLOT (NCH + 1)    // 129 checkpoint slots per (dir,b)

__device__ __forceinline__ float sigm(float x) { return 1.f / (1.f + expf(-x)); }
__device__ __forceinline__ float tanh_f(float x) { float e = expf(2.f * x); return 1.f - 2.f / (e + 1.f); }

// ---------------- Kernel A: layer-0 pass, store (h,c) checkpoints every CK steps ----------------
__global__ __launch_bounds__(256, 1) void lstm_ckpt(
    const float* __restrict__ x,      // [B][T][2]
    const float* __restrict__ w_ih,   // [2][256][2]
    const float* __restrict__ w_hh,   // [2][256][64]
    const float* __restrict__ b_ih, const float* __restrict__ b_hh,
    float* __restrict__ ckpt)         // [2][B][NSLOT][128] (h:0..63, c:64..127)
{
    const int blk = blockIdx.x;
    const int dir = blk & 1;
    const int b   = blk >> 1;
    const int tid = threadIdx.x;

    __shared__ __align__(16) float xs[TT * 2];
    __shared__ __align__(16) float h_lds[HID];
    __shared__ __align__(16) float g_lds[256];

    {
        const float4* src = (const float4*)(x + (size_t)b * TT * 2);
        float4* dst = (float4*)xs;
        #pragma unroll
        for (int r = 0; r < 8; ++r) dst[tid + r * 256] = src[tid + r * 256];
    }
    const int row = dir * 256 + tid;
    float wv[HID];
    {
        const float4* wr = (const float4*)(w_hh + (size_t)row * HID);
        #pragma unroll
        for (int k = 0; k < 16; ++k) {
            float4 v = wr[k];
            wv[4*k] = v.x; wv[4*k+1] = v.y; wv[4*k+2] = v.z; wv[4*k+3] = v.w;
        }
    }
    const float wx0 = w_ih[row * 2 + 0], wx1 = w_ih[row * 2 + 1];
    const float bias = b_ih[row] + b_hh[row];
    const int gtype = tid >> 6;
    float c = 0.f, hreg = 0.f;
    if (tid < HID) h_lds[tid] = 0.f;
    __syncthreads();

    for (int t = 0; t < TT; ++t) {
        const int tt = dir ? (TT - 1 - t) : t;
        if (tid < HID) {
            const int bnum = dir ? (tt + 1) : tt;   // state BEFORE processing tt
            if ((bnum & (CK - 1)) == 0) {
                float* cp = ckpt + (((size_t)(dir * BATCH + b) * NSLOT + (bnum >> 5)) << 7);
                cp[tid] = hreg; cp[HID + tid] = c;
            }
        }
        const float base = bias + wx0 * xs[tt * 2] + wx1 * xs[tt * 2 + 1];
        float a0 = 0.f, a1 = 0.f, a2 = 0.f, a3 = 0.f;
        const float4* h4 = (const float4*)h_lds;
        #pragma unroll
        for (int k = 0; k < 16; ++k) {
            float4 hv = h4[k];
            a0 = fmaf(wv[4*k],   hv.x, a0);
            a1 = fmaf(wv[4*k+1], hv.y, a1);
            a2 = fmaf(wv[4*k+2], hv.z, a2);
            a3 = fmaf(wv[4*k+3], hv.w, a3);
        }
        const float acc = base + ((a0 + a1) + (a2 + a3));
        g_lds[tid] = (gtype == 2) ? tanh_f(acc) : sigm(acc);
        __syncthreads();
        if (tid < HID) {
            const float iv = g_lds[tid], fv = g_lds[64 + tid], gg = g_lds[128 + tid], ov = g_lds[192 + tid];
            c = fv * c + iv * gg;
            hreg = ov * tanh_f(c);
            h_lds[tid] = hreg;
        }
        __syncthreads();
    }
}

// ---------------- Kernel B: fused layer-1 + layer-0 recompute + FC logits ----------------
// 1024 threads: tid<512 = L1 (row=tid>>1, half=tid&1); 512..767 = L0-fwd; 768..1023 = L0-bwd.
__global__ __launch_bounds__(1024) void lstm_fused1(
    const float* __restrict__ x,
    const float* __restrict__ w_ih0, const float* __restrict__ w_hh0,
    const float* __restrict__ b_ih0, const float* __restrict__ b_hh0,
    const float* __restrict__ w_ih1, const float* __restrict__ w_hh1,
    const float* __restrict__ b_ih1, const float* __restrict__ b_hh1,
    const float* __restrict__ fc_w,  const float* __restrict__ ckpt,
    float* __restrict__ plog)        // [2][B][T][2]
{
    const int blk = blockIdx.x;
    const int l1dir = blk & 1;
    const int b = blk >> 1;
    const int tid = threadIdx.x;

    __shared__ __align__(16) float h0buf[2][CK][128];
    __shared__ __align__(16) float xbuf[2][CK][2];
    __shared__ __align__(16) float g1[256];
    __shared__ __align__(16) float g0[2][256];
    __shared__ __align__(16) float h1_lds[HID];
    __shared__ __align__(16) float h0s[2][HID];

    const bool isL1 = (tid < 512);
    const int l1row = tid >> 1;
    const int l1half = tid & 1;
    const int d0 = (tid >> 8) - 2;     // 0 fwd, 1 bwd (valid when !isL1)
    const int st0 = tid & 255;

    float wreg[96];                    // overlaid: L1 = 96 weights; L0 = wh[64] + wx[2]
    float bias_, fw0 = 0.f, fw1 = 0.f;
    int gtype_;
    float c_state = 0.f, ckh = 0.f, ckc = 0.f;
    float4 xpre = make_float4(0.f, 0.f, 0.f, 0.f);

    if (isL1) {
        const int grow = l1dir * 256 + l1row;
        const float* wi = w_ih1 + (size_t)grow * 128;
        const float* wh = w_hh1 + (size_t)grow * 64;
        const float4* srcA = (const float4*)wi + (l1half ? 24 : 0);
        const float4* srcB = l1half ? (const float4*)wh : ((const float4*)wi + 8);
        #pragma unroll
        for (int k = 0; k < 8; ++k) {
            float4 v = srcA[k];
            wreg[4*k] = v.x; wreg[4*k+1] = v.y; wreg[4*k+2] = v.z; wreg[4*k+3] = v.w;
        }
        #pragma unroll
        for (int k = 0; k < 16; ++k) {
            float4 v = srcB[k];
            wreg[32+4*k] = v.x; wreg[32+4*k+1] = v.y; wreg[32+4*k+2] = v.z; wreg[32+4*k+3] = v.w;
        }
        bias_ = b_ih1[grow] + b_hh1[grow];
        gtype_ = l1row >> 6;
    } else {
        const int growd = d0 * 256 + st0;
        const float4* wh = (const float4*)(w_hh0 + (size_t)growd * 64);
        #pragma unroll
        for (int k = 0; k < 16; ++k) {
            float4 v = wh[k];
            wreg[4*k] = v.x; wreg[4*k+1] = v.y; wreg[4*k+2] = v.z; wreg[4*k+3] = v.w;
        }
        wreg[64] = w_ih0[growd * 2 + 0];
        wreg[65] = w_ih0[growd * 2 + 1];
        bias_ = b_ih0[growd] + b_hh0[growd];
        gtype_ = st0 >> 6;
        if (d0 == 1 && st0 >= 64 && st0 < 128) {   // logit wave
            fw0 = fc_w[l1dir * 64 + (st0 - 64)];
            fw1 = fc_w[128 + l1dir * 64 + (st0 - 64)];
        }
    }

    // initial loads: x chunk seq0, ckpt seq0
    if (tid < HID) h1_lds[tid] = 0.f;
    {
        const int ch0 = l1dir ? (NCH - 1) : 0;
        if (tid < 16)
            ((float4*)xbuf[0])[tid] = ((const float4*)(x + ((size_t)b * TT + (size_t)ch0 * CK) * 2))[tid];
        if (!isL1 && st0 < HID) {
            const int slot = d0 ? (ch0 + 1) : ch0;
            const float* cp = ckpt + (((size_t)(d0 * BATCH + b) * NSLOT + slot) << 7);
            h0s[d0][st0] = cp[st0];
            c_state = cp[HID + st0];
        }
    }
    __syncthreads();

    auto stepf = [&](int s, int ml, int mc, int mp) {
        // ---------- phase A: gates / logits / prefetch ----------
        if (s == 0 && mp >= 0 && !isL1) {
            const int chp = l1dir ? (NCH - 1 - mp) : mp;
            if (st0 < HID) {
                const int slot = d0 ? (chp + 1) : chp;
                const float* cp = ckpt + (((size_t)(d0 * BATCH + b) * NSLOT + slot) << 7);
                ckh = cp[st0]; ckc = cp[HID + st0];
            }
            if (d0 == 1 && st0 >= 128 && st0 < 144)
                xpre = ((const float4*)(x + ((size_t)b * TT + (size_t)chp * CK) * 2))[st0 - 128];
        }
        if (isL1) {
            if (ml >= 0) {
                const int trow = l1dir ? (CK - 1 - s) : s;
                const float* h0row = h0buf[ml & 1][trow];
                const float4* pA = (const float4*)h0row + (l1half ? 24 : 0);
                const float4* pB = l1half ? (const float4*)h1_lds : ((const float4*)h0row + 8);
                float a0 = 0.f, a1 = 0.f, a2 = 0.f, a3 = 0.f;
                #pragma unroll
                for (int k = 0; k < 8; ++k) {
                    float4 v = pA[k];
                    a0 = fmaf(wreg[4*k],   v.x, a0);
                    a1 = fmaf(wreg[4*k+1], v.y, a1);
                    a2 = fmaf(wreg[4*k+2], v.z, a2);
                    a3 = fmaf(wreg[4*k+3], v.w, a3);
                }
                #pragma unroll
                for (int k = 0; k < 16; ++k) {
                    float4 v = pB[k];
                    a0 = fmaf(wreg[32+4*k],   v.x, a0);
                    a1 = fmaf(wreg[32+4*k+1], v.y, a1);
                    a2 = fmaf(wreg[32+4*k+2], v.z, a2);
                    a3 = fmaf(wreg[32+4*k+3], v.w, a3);
                }
                float tot = (a0 + a1) + (a2 + a3);
                tot += __shfl_xor(tot, 1);
                tot += bias_;
                const float gv = (gtype_ == 2) ? tanh_f(tot) : sigm(tot);
                if (l1half == 0) g1[l1row] = gv;
            }
        } else {
            if (mc >= 0) {
                const int r0 = d0 ? (CK - 1 - s) : s;
                const float4* hsrc = (const float4*)h0s[d0];
                float a0 = 0.f, a1 = 0.f, a2 = 0.f, a3 = 0.f;
                #pragma unroll
                for (int k = 0; k < 16; ++k) {
                    float4 v = hsrc[k];
                    a0 = fmaf(wreg[4*k],   v.x, a0);
                    a1 = fmaf(wreg[4*k+1], v.y, a1);
                    a2 = fmaf(wreg[4*k+2], v.z, a2);
                    a3 = fmaf(wreg[4*k+3], v.w, a3);
                }
                float tot = (a0 + a1) + (a2 + a3) + bias_
                          + wreg[64] * xbuf[mc & 1][r0][0] + wreg[65] * xbuf[mc & 1][r0][1];
                const float gv = (gtype_ == 2) ? tanh_f(tot) : sigm(tot);
                g0[d0][st0] = gv;
            }
            if (d0 == 1 && st0 >= 64 && st0 < 128 && ml >= 0) {
                const int gt = ml * CK + s;
                if (gt > 0) {
                    const int l = st0 - 64;
                    const float hv = h1_lds[l];
                    float p0 = hv * fw0, p1 = hv * fw1;
                    #pragma unroll
                    for (int d_ = 32; d_ > 0; d_ >>= 1) { p0 += __shfl_xor(p0, d_); p1 += __shfl_xor(p1, d_); }
                    if (l == 0) {
                        const int tp = l1dir ? (TT - gt) : (gt - 1);
                        *(float2*)(plog + (((size_t)l1dir * BATCH + b) * TT + tp) * 2) = make_float2(p0, p1);
                    }
                }
            }
        }
        __syncthreads();
        // ---------- phase C: state updates / boundary ----------
        if (isL1) {
            if (ml >= 0 && tid < HID) {
                const float iv = g1[tid], fv = g1[64 + tid], gg = g1[128 + tid], ov = g1[192 + tid];
                c_state = fv * c_state + iv * gg;
                h1_lds[tid] = ov * tanh_f(c_state);
            }
        } else {
            if (mc >= 0 && st0 < HID) {
                const float iv = g0[d0][st0], fv = g0[d0][64 + st0], gg = g0[d0][128 + st0], ov = g0[d0][192 + st0];
                c_state = fv * c_state + iv * gg;
                const float hv = ov * tanh_f(c_state);
                const int orow = d0 ? (CK - 1 - s) : s;
                h0buf[mc & 1][orow][d0 * HID + st0] = hv;
                if (s == CK - 1 && mp >= 0) { h0s[d0][st0] = ckh; c_state = ckc; }
                else h0s[d0][st0] = hv;
            }
            if (s == CK - 1 && mp >= 0 && d0 == 1 && st0 >= 128 && st0 < 144)
                ((float4*)xbuf[mp & 1])[st0 - 128] = xpre;
        }
        __syncthreads();
    };

    // prologue: L0 computes chunk seq 0 into buf0; prefetch seq 1
    for (int s = 0; s < CK; ++s) stepf(s, -1, 0, 1);
    // main phases: L1 consumes seq i; L0 computes seq i+1; prefetch seq i+2
    for (int i = 0; i < NCH; ++i) {
        const int mc = (i + 1 < NCH) ? (i + 1) : -1;
        const int mp = (i + 2 < NCH) ? (i + 2) : -1;
        for (int s = 0; s < CK; ++s) stepf(s, i, mc, mp);
    }
    // final logits (gt = TT)
    if (!isL1 && d0 == 1 && st0 >= 64 && st0 < 128) {
        const int l = st0 - 64;
        const float hv = h1_lds[l];
        float p0 = hv * fw0, p1 = hv * fw1;
        #pragma unroll
        for (int d_ = 32; d_ > 0; d_ >>= 1) { p0 += __shfl_xor(p0, d_); p1 += __shfl_xor(p1, d_); }
        if (l == 0) {
            const int tp = l1dir ? 0 : (TT - 1);
            *(float2*)(plog + (((size_t)l1dir * BATCH + b) * TT + tp) * 2) = make_float2(p0, p1);
        }
    }
}

// ---------------- Kernel C: fused Viterbi (max-plus parallel scan + backtrack) ----------------
__device__ __forceinline__ unsigned long long shfl_u64(unsigned long long v, int src) {
    unsigned int lo = (unsigned int)v, hi = (unsigned int)(v >> 32);
    lo = __shfl(lo, src); hi = __shfl(hi, src);
    return ((unsigned long long)hi << 32) | lo;
}

__global__ __launch_bounds__(64, 1) void viterbi_k(
    const float* __restrict__ plog, const float* __restrict__ fc_b,
    const float* __restrict__ trans, const float* __restrict__ startv,
    const float* __restrict__ endv, int* __restrict__ out)
{
    const int b = blockIdx.x;
    const int lane = threadIdx.x;
    __shared__ __align__(16) float2 e_lds[64][65];   // [t&63][t>>6], padded

    const float fb0 = fc_b[0], fb1 = fc_b[1];
    const float* pf = plog + ((size_t)(0 * BATCH + b) * TT) * 2;
    const float* pb = plog + ((size_t)(1 * BATCH + b) * TT) * 2;
    for (int r = 0; r < 32; ++r) {
        const int i4 = r * 64 + lane;            // covers t = 2*i4, 2*i4+1
        float4 a = ((const float4*)pf)[i4];
        float4 cc = ((const float4*)pb)[i4];
        const int t0 = 2 * i4, t1 = t0 + 1;
        e_lds[t0 & 63][t0 >> 6] = make_float2(a.x + cc.x + fb0, a.y + cc.y + fb1);
        e_lds[t1 & 63][t1 >> 6] = make_float2(a.z + cc.z + fb0, a.w + cc.w + fb1);
    }
    __syncthreads();
    const float tr00 = trans[0], tr01 = trans[1], tr10 = trans[2], tr11 = trans[3];
    const float2 e0 = e_lds[0][0];
    const float s00 = startv[0] + e0.x, s01 = startv[1] + e0.y;   // score at t=0

    const int lo = lane * 64;
    const int hi = (lane == 63) ? (TT - 1) : (lo + 64);
    // pass 1: chunk max-plus matrix A (maps score@lo -> score@hi)
    float a00, a01, a10, a11;
    {
        const float2 ee = e_lds[(lo + 1) & 63][(lo + 1) >> 6];
        a00 = tr00 + ee.x; a01 = tr01 + ee.y; a10 = tr10 + ee.x; a11 = tr11 + ee.y;
    }
    for (int t = lo + 2; t <= hi; ++t) {
        const float2 ee = e_lds[t & 63][t >> 6];
        const float n00 = fmaxf(a00 + tr00, a01 + tr10) + ee.x;
        const float n01 = fmaxf(a00 + tr01, a01 + tr11) + ee.y;
        const float n10 = fmaxf(a10 + tr00, a11 + tr10) + ee.x;
        const float n11 = fmaxf(a10 + tr01, a11 + tr11) + ee.y;
        a00 = n00; a01 = n01; a10 = n10; a11 = n11;
    }
    // inclusive scan: lane i -> A_0 ∘ ... ∘ A_i  (earlier left)
    #pragma unroll
    for (int d = 1; d < 64; d <<= 1) {
        const float o00 = __shfl_up(a00, d), o01 = __shfl_up(a01, d);
        const float o10 = __shfl_up(a10, d), o11 = __shfl_up(a11, d);
        if (lane >= d) {
            const float n00 = fmaxf(o00 + a00, o01 + a10);
            const float n01 = fmaxf(o00 + a01, o01 + a11);
            const float n10 = fmaxf(o10 + a00, o11 + a10);
            const float n11 = fmaxf(o10 + a01, o11 + a11);
            a00 = n00; a01 = n01; a10 = n10; a11 = n11;
        }
    }
    // entry score at t=lo
    const float p00 = __shfl_up(a00, 1), p01 = __shfl_up(a01, 1);
    const float p10 = __shfl_up(a10, 1), p11 = __shfl_up(a11, 1);
    float s0, s1;
    if (lane == 0) { s0 = s00; s1 = s01; }
    else { s0 = fmaxf(s00 + p00, s01 + p10); s1 = fmaxf(s00 + p01, s01 + p11); }
    // re-walk, record bp bits (bit s = decision at t=lo+1+s)
    unsigned long long m0 = 0ull, m1 = 0ull;
    for (int t = lo + 1; t <= hi; ++t) {
        const float2 ee = e_lds[t & 63][t >> 6];
        const float c00 = s0 + tr00, c10 = s1 + tr10;
        const float c01 = s0 + tr01, c11 = s1 + tr11;
        const int bp0 = c10 > c00, bp1 = c11 > c01;   // strict >: first-index tiebreak
        s0 = (bp0 ? c10 : c00) + ee.x;
        s1 = (bp1 ? c11 : c01) + ee.y;
        m0 |= (unsigned long long)bp0 << (t - lo - 1);
        m1 |= (unsigned long long)bp1 << (t - lo - 1);
    }
    // last tag (lane 63 holds final scores)
    int last;
    {
        const int lt = (s1 + endv[1]) > (s0 + endv[0]);
        last = __shfl(lt, 63);
    }
    // chunk map F: tag@hi -> tag@lo
    int f0 = 0, f1 = 1;
    for (int t = hi; t > lo; --t) {
        const int s_ = t - lo - 1;
        f0 = (int)(((f0 ? m1 : m0) >> s_) & 1ull);
        f1 = (int)(((f1 ? m1 : m0) >> s_) & 1ull);
    }
    int mm = f0 | (f1 << 1);
    // suffix scan: G_i = F_i ∘ G_{i+d}
    #pragma unroll
    for (int d = 1; d < 64; d <<= 1) {
        const int mo = __shfl_down(mm, d);
        if (lane + d < 64) {
            const int r0 = (mm >> (mo & 1)) & 1;
            const int r1 = (mm >> ((mo >> 1) & 1)) & 1;
            mm = r0 | (r1 << 1);
        }
    }
    const int gn = __shfl_down(mm, 1);
    int cur = (lane == 63) ? last : ((gn >> last) & 1);   // tag at t=hi
    unsigned long long tagm = 0ull;                        // bit s = tag at t=lo+s
    if (lane == 63) tagm |= (unsigned long long)last << 63;
    for (int t = hi; t > lo; --t) {
        const int s_ = t - lo - 1;
        cur = (int)(((cur ? m1 : m0) >> s_) & 1ull);
        tagm |= (unsigned long long)cur << s_;
    }
    // output: t = r*64 + lane -> lane r's bit 'lane'
    int* ob = out + (size_t)b * TT;
    for (int r = 0; r < 64; ++r) {
        const unsigned long long mr = shfl_u64(tagm, r);
        ob[r * 64 + lane] = (int)((mr >> lane) & 1ull);
    }
}

extern "C" void kernel_launch(void* const* d_in, const int* in_sizes, int n_in,
                              void* d_out, int out_size, void* d_ws, size_t ws_size,
                              hipStream_t stream) {
    const float* x      = (const float*)d_in[0];
    const float* w_ih0  = (const float*)d_in[1];
    const float* w_hh0  = (const float*)d_in[2];
    const float* b_ih0  = (const float*)d_in[3];
    const float* b_hh0  = (const float*)d_in[4];
    const float* w_ih1  = (const float*)d_in[5];
    const float* w_hh1  = (const float*)d_in[6];
    const float* b_ih1  = (const float*)d_in[7];
    const float* b_hh1  = (const float*)d_in[8];
    const float* fc_w   = (const float*)d_in[9];
    const float* fc_b   = (const float*)d_in[10];
    const float* trans  = (const float*)d_in[11];
    const float* startv = (const float*)d_in[12];
    const float* endv   = (const float*)d_in[13];

    char* ws = (char*)d_ws;
    const size_t ckpt_bytes = (size_t)2 * BATCH * NSLOT * 128 * 4;   // 16,908,288 B
    float* ckpt = (float*)ws;
    float* plog = (float*)(ws + ckpt_bytes);                          // 8,388,608 B

    lstm_ckpt<<<256, 256, 0, stream>>>(x, w_ih0, w_hh0, b_ih0, b_hh0, ckpt);
    lstm_fused1<<<256, 1024, 0, stream>>>(x, w_ih0, w_hh0, b_ih0, b_hh0,
                                          w_ih1, w_hh1, b_ih1, b_hh1,
                                          fc_w, ckpt, plog);
    viterbi_k<<<128, 64, 0, stream>>>(plog, fc_b, trans, startv, endv, (int*)d_out);
}